// Round 4
// baseline (461.616 us; speedup 1.0000x reference)
//
#include <hip/hip_runtime.h>
#include <hip/hip_bf16.h>
#include <cstdint>

typedef _Float16 f16;
typedef f16 f16x8 __attribute__((ext_vector_type(8)));
typedef f16 f16x4 __attribute__((ext_vector_type(4)));
typedef float f32x4 __attribute__((ext_vector_type(4)));

#define MFMA16(a, b, c) __builtin_amdgcn_mfma_f32_16x16x32_f16((a), (b), (c), 0, 0, 0)

constexpr int Bc = 4, Sc = 2048, Dc = 1024, Hc = 16, DHc = 64;

// direct global->LDS async copy, 16B per lane. LDS dest = wave-uniform base +
// lane*16 (m104). C-style casts perform the generic->AS(1)/AS(3) conversion.
typedef __attribute__((address_space(1))) const uint32_t gbl_u32;
typedef __attribute__((address_space(3))) uint32_t lds_u32;
__device__ __forceinline__ void gld_lds16(const void* g, void* l) {
  __builtin_amdgcn_global_load_lds((gbl_u32*)g, (lds_u32*)l, 16, 0, 0);
}

// ---------------------------------------------------------------------------
// Kernel 1: cast+transpose weights: W fp32 [K=1024][N=1024] -> Wt f16 [z][N][K]
// ---------------------------------------------------------------------------
__global__ __launch_bounds__(256) void cast_w_kernel(
    const float* __restrict__ Wq, const float* __restrict__ Wk,
    const float* __restrict__ Wv, f16* __restrict__ Wt) {
  __shared__ __align__(16) f16 T[64][66];
  const int z = blockIdx.z;
  const float* W = (z == 0) ? Wq : (z == 1) ? Wk : Wv;
  const int n0 = blockIdx.x * 64, k0 = blockIdx.y * 64;
  const int t = threadIdx.x;
#pragma unroll
  for (int p = 0; p < 4; p++) {
    int idx = t + p * 256;
    int r = idx >> 4, c = idx & 15;
    float4 v = *(const float4*)(W + (size_t)(k0 + r) * Dc + n0 + c * 4);
    T[r][c * 4 + 0] = (f16)v.x;
    T[r][c * 4 + 1] = (f16)v.y;
    T[r][c * 4 + 2] = (f16)v.z;
    T[r][c * 4 + 3] = (f16)v.w;
  }
  __syncthreads();
#pragma unroll
  for (int p = 0; p < 2; p++) {
    int idx = t + p * 256;
    int n = idx >> 3, c = idx & 7;
    f16x8 tmp;
#pragma unroll
    for (int j = 0; j < 8; j++) tmp[j] = T[c * 8 + j][n];
    *(f16x8*)(Wt + ((size_t)z * Dc + n0 + n) * Dc + k0 + c * 8) = tmp;
  }
}

// ---------------------------------------------------------------------------
// Kernel 1b: cast X fp32 -> f16 (so the GEMM can use global_load_lds).
// ---------------------------------------------------------------------------
__global__ __launch_bounds__(256) void cast_x_kernel(const float* __restrict__ X,
                                                     f16* __restrict__ X16) {
  size_t i = ((size_t)blockIdx.x * 256 + threadIdx.x) * 8;
  float4 a = *(const float4*)(X + i);
  float4 b = *(const float4*)(X + i + 4);
  f16x8 h;
  h[0] = (f16)a.x; h[1] = (f16)a.y; h[2] = (f16)a.z; h[3] = (f16)a.w;
  h[4] = (f16)b.x; h[5] = (f16)b.y; h[6] = (f16)b.z; h[7] = (f16)b.w;
  *(f16x8*)(X16 + i) = h;
}

// ---------------------------------------------------------------------------
// Kernel 2: QKV GEMM, m97-style (unchanged this round).
// ---------------------------------------------------------------------------
__global__ __launch_bounds__(256) void qkv_gemm_kernel(
    const f16* __restrict__ X16, const f16* __restrict__ Wt,
    const float* __restrict__ bq, const float* __restrict__ bk,
    const float* __restrict__ bv, f16* __restrict__ Qo, f16* __restrict__ Ko,
    f16* __restrict__ Vo) {
  const int z = blockIdx.z;
  const f16* W = Wt + (size_t)z * Dc * Dc;
  const float* bias = (z == 0) ? bq : (z == 1) ? bk : bv;

  const int n0 = blockIdx.x * 128, m0 = blockIdx.y * 128;
  __shared__ __align__(16) f16 Xs[128 * 32];
  __shared__ __align__(16) f16 Ws[128 * 32];

  const int t = threadIdx.x;
  const int wave = t >> 6, lane = t & 63;
  const int l16 = lane & 15, quad = lane >> 4;
  const int wm = (wave >> 1) * 64, wn = (wave & 1) * 64;

  f32x4 acc[4][4];
#pragma unroll
  for (int i = 0; i < 4; i++)
#pragma unroll
    for (int j = 0; j < 4; j++) acc[i][j] = (f32x4){0.f, 0.f, 0.f, 0.f};

  for (int k0 = 0; k0 < Dc; k0 += 32) {
#pragma unroll
    for (int p = 0; p < 2; p++) {
      int cb = p * 256 + wave * 64;  // wave-uniform chunk base
      int chunk = cb + lane;
      int row = chunk >> 2, c8 = (chunk & 3) * 8;
      gld_lds16(X16 + (size_t)(m0 + row) * Dc + k0 + c8, (f16*)Xs + (size_t)cb * 8);
      gld_lds16(W + (size_t)(n0 + row) * Dc + k0 + c8, (f16*)Ws + (size_t)cb * 8);
    }
    __syncthreads();

    f16x8 aF[4], bF[4];
#pragma unroll
    for (int mt = 0; mt < 4; mt++)
      aF[mt] = *(const f16x8*)(&Xs[(wm + mt * 16 + l16) * 32 + quad * 8]);
#pragma unroll
    for (int nt = 0; nt < 4; nt++)
      bF[nt] = *(const f16x8*)(&Ws[(wn + nt * 16 + l16) * 32 + quad * 8]);
#pragma unroll
    for (int mt = 0; mt < 4; mt++)
#pragma unroll
      for (int nt = 0; nt < 4; nt++)
        acc[mt][nt] = MFMA16(aF[mt], bF[nt], acc[mt][nt]);
    __syncthreads();
  }

#pragma unroll
  for (int nt = 0; nt < 4; nt++) {
    int col = n0 + wn + nt * 16 + l16;
    float bval = bias[col];
    int h = col >> 6, d = col & 63;
    if (z == 2) {
#pragma unroll
      for (int mt = 0; mt < 4; mt++) {
        int m = m0 + wm + mt * 16 + quad * 4;
        int b = m >> 11, sbase = m & 2047;
        f16x4 pk;
#pragma unroll
        for (int r = 0; r < 4; r++) pk[r] = (f16)(acc[mt][nt][r] + bval);
        *(f16x4*)(Vo + (((size_t)(b * Hc + h)) * DHc + d) * Sc + sbase) = pk;
      }
    } else {
      const float sc = (z == 0) ? 0.125f : 1.0f;
      f16* O = (z == 0) ? Qo : Ko;
#pragma unroll
      for (int mt = 0; mt < 4; mt++) {
#pragma unroll
        for (int r = 0; r < 4; r++) {
          int m = m0 + wm + mt * 16 + quad * 4 + r;
          int b = m >> 11, s = m & 2047;
          O[(((size_t)(b * Hc + h)) * Sc + s) * DHc + d] =
              (f16)((acc[mt][nt][r] + bval) * sc);
        }
      }
    }
  }
}

// ---------------------------------------------------------------------------
// Kernel 3: flash attention, KEY-SPLIT across waves.
// Block = 32 queries; wave w owns keys [w*512, w*512+512) (8 chunks of 64).
// No-max softmax is associative -> no online rescaling; waves merge o,l once
// at the end (3 barriers total; main loop barrier-free). K-frags register-
// prefetched one chunk ahead. bh = fid&63 groups same-bh blocks on one XCD
// residue so K/V stay in one L2 (8 bh/XCD * 512 KB = 4 MB).
// grid: 4096 blocks (64 q-tiles x 64 bh), 256 threads.
// ---------------------------------------------------------------------------
__global__ __launch_bounds__(256, 3) void flash_kernel(
    const f16* __restrict__ Q, const f16* __restrict__ K,
    const f16* __restrict__ Vt, const float* __restrict__ mask,
    float* __restrict__ out) {
  const int fid = blockIdx.x;
  const int bh = fid & 63;   // XCD-L2 locality: same-bh blocks -> same residue
  const int qtile = fid >> 6;
  const int b = bh >> 4, h = bh & 15;
  const int q0 = qtile * 32;
  const int t = threadIdx.x;
  const int wave = t >> 6, lane = t & 63;
  const int l16 = lane & 15, quad = lane >> 4;

  // per-wave region: Pbuf [2][16][76] f16 = 4864 B; reused as reduction
  // buffer float[64][18] = 4608 B at the end.
  __shared__ __align__(16) uint8_t smem[4][4864];
  f16* pb = (f16*)&smem[wave][0];

  const f16* Kb = K + (size_t)bh * Sc * DHc;
  const f16* Vb = Vt + (size_t)bh * DHc * Sc;
  const float* mrow = mask + (size_t)b * Sc;

  // Q as B-operand frags (all waves: same 32 queries; L1-shared)
  f16x8 qa[2][2];
#pragma unroll
  for (int mt = 0; mt < 2; mt++) {
    const f16* qb = Q + ((size_t)bh * Sc + q0 + mt * 16 + l16) * DHc;
    qa[mt][0] = *(const f16x8*)(qb + quad * 8);
    qa[mt][1] = *(const f16x8*)(qb + 32 + quad * 8);
  }

  float l_acc[2] = {0.f, 0.f};
  f32x4 o[2][4];
#pragma unroll
  for (int mt = 0; mt < 2; mt++)
#pragma unroll
    for (int dt = 0; dt < 4; dt++) o[mt][dt] = (f32x4){0.f, 0.f, 0.f, 0.f};

  const int kbase = wave * 512, kend = kbase + 512;

  // preload K frags for first chunk (A-operand: m=l16 -> key, k -> dh)
  f16x8 ka[4][2];
#pragma unroll
  for (int nt = 0; nt < 4; nt++) {
    const f16* kp = Kb + (size_t)(kbase + nt * 16 + l16) * DHc;
    ka[nt][0] = *(const f16x8*)(kp + quad * 8);
    ka[nt][1] = *(const f16x8*)(kp + 32 + quad * 8);
  }

  for (int c0 = kbase; c0 < kend; c0 += 64) {
    // prefetch next chunk's K (wraps harmlessly on last iter)
    const int cn = (c0 + 64 < kend) ? c0 + 64 : kbase;
    f16x8 kn[4][2];
#pragma unroll
    for (int nt = 0; nt < 4; nt++) {
      const f16* kp = Kb + (size_t)(cn + nt * 16 + l16) * DHc;
      kn[nt][0] = *(const f16x8*)(kp + quad * 8);
      kn[nt][1] = *(const f16x8*)(kp + 32 + quad * 8);
    }
    float4 mv[4];
#pragma unroll
    for (int nt = 0; nt < 4; nt++)
      mv[nt] = *(const float4*)(mrow + c0 + nt * 16 + quad * 4);

#pragma unroll
    for (int mt = 0; mt < 2; mt++) {
      // S^T = K*Q^T + mask (mask folded into accumulator init)
      f32x4 s[4];
#pragma unroll
      for (int nt = 0; nt < 4; nt++) {
        f32x4 a = (f32x4){mv[nt].x, mv[nt].y, mv[nt].z, mv[nt].w};
        a = MFMA16(ka[nt][0], qa[mt][0], a);
        a = MFMA16(ka[nt][1], qa[mt][1], a);
        s[nt] = a;
      }
      float ls = 0.f;
#pragma unroll
      for (int nt = 0; nt < 4; nt++)
#pragma unroll
        for (int r = 0; r < 4; r++) {
          float p = __expf(s[nt][r]);
          s[nt][r] = p;
          ls += p;
        }
      l_acc[mt] += ls;
#pragma unroll
      for (int nt = 0; nt < 4; nt++) {
        f16x4 pk;
#pragma unroll
        for (int r = 0; r < 4; r++) pk[r] = (f16)s[nt][r];
        *(f16x4*)(pb + (mt * 16 + l16) * 76 + nt * 16 + quad * 4) = pk;
      }
    }

    // read P A-frags (b64 pairs, stride 76 = bank floor)
    f16x8 pa[2][2];
#pragma unroll
    for (int mt = 0; mt < 2; mt++) {
      const f16* prow = pb + (mt * 16 + l16) * 76;
      f16x4 a0 = *(const f16x4*)(prow + quad * 8);
      f16x4 a1 = *(const f16x4*)(prow + quad * 8 + 4);
      pa[mt][0] = __builtin_shufflevector(a0, a1, 0, 1, 2, 3, 4, 5, 6, 7);
      f16x4 b0 = *(const f16x4*)(prow + 32 + quad * 8);
      f16x4 b1 = *(const f16x4*)(prow + 32 + quad * 8 + 4);
      pa[mt][1] = __builtin_shufflevector(b0, b1, 0, 1, 2, 3, 4, 5, 6, 7);
    }

    // PV (V^T frags shared across both m-tiles)
#pragma unroll
    for (int dt = 0; dt < 4; dt++) {
      const f16* vp = Vb + (size_t)(dt * 16 + l16) * Sc + c0;
      f16x8 v0 = *(const f16x8*)(vp + quad * 8);
      f16x8 v1 = *(const f16x8*)(vp + 32 + quad * 8);
      o[0][dt] = MFMA16(pa[0][0], v0, o[0][dt]);
      o[0][dt] = MFMA16(pa[0][1], v1, o[0][dt]);
      o[1][dt] = MFMA16(pa[1][0], v0, o[1][dt]);
      o[1][dt] = MFMA16(pa[1][1], v1, o[1][dt]);
    }

#pragma unroll
    for (int nt = 0; nt < 4; nt++) {
      ka[nt][0] = kn[nt][0];
      ka[nt][1] = kn[nt][1];
    }
  }

  // ---- cross-wave merge: o and l are plain sums over key strips ----
#pragma unroll
  for (int mt = 0; mt < 2; mt++) {
    float* rd = (float*)&smem[wave][0];
#pragma unroll
    for (int dt = 0; dt < 4; dt++)
      *(f32x4*)(rd + lane * 18 + dt * 4) = o[mt][dt];
    rd[lane * 18 + 16] = l_acc[mt];
    __syncthreads();
    if (wave == 0) {
#pragma unroll
      for (int w = 1; w < 4; w++) {
        const float* rs = (const float*)&smem[w][0];
#pragma unroll
        for (int dt = 0; dt < 4; dt++)
          o[mt][dt] += *(const f32x4*)(rs + lane * 18 + dt * 4);
        l_acc[mt] += rs[lane * 18 + 16];
      }
    }
    __syncthreads();
  }
  if (wave != 0) return;

  // ---- epilogue (wave 0): reduce l across quads, normalize, store ----
#pragma unroll
  for (int mt = 0; mt < 2; mt++) {
    l_acc[mt] += __shfl_xor(l_acc[mt], 16);
    l_acc[mt] += __shfl_xor(l_acc[mt], 32);
  }
#pragma unroll
  for (int mt = 0; mt < 2; mt++) {
    float inv[4];
#pragma unroll
    for (int r = 0; r < 4; r++)
      inv[r] = 1.0f / __shfl(l_acc[mt], quad * 4 + r);
#pragma unroll
    for (int dt = 0; dt < 4; dt++) {
      int col = h * 64 + dt * 16 + l16;
#pragma unroll
      for (int r = 0; r < 4; r++) {
        int row = q0 + mt * 16 + quad * 4 + r;
        out[((size_t)b * Sc + row) * Dc + col] = o[mt][dt][r] * inv[r];
      }
    }
  }
}

// ---------------------------------------------------------------------------
extern "C" void kernel_launch(void* const* d_in, const int* in_sizes, int n_in,
                              void* d_out, int out_size, void* d_ws,
                              size_t ws_size, hipStream_t stream) {
  (void)in_sizes; (void)n_in; (void)out_size; (void)ws_size;
  const float* hidden = (const float*)d_in[0];
  const float* mask   = (const float*)d_in[1];
  const float* Wq     = (const float*)d_in[2];
  const float* bq     = (const float*)d_in[3];
  const float* Wk     = (const float*)d_in[4];
  const float* bk     = (const float*)d_in[5];
  const float* Wv     = (const float*)d_in[6];
  const float* bv     = (const float*)d_in[7];
  float* out = (float*)d_out;

  uint8_t* w = (uint8_t*)d_ws;
  f16* Wt   = (f16*)(w);                               //  6 MB
  f16* X16  = (f16*)(w + (size_t)6 * 1024 * 1024);     // 16 MB
  f16* Q16  = (f16*)(w + (size_t)22 * 1024 * 1024);    // 16 MB (pre-scaled)
  f16* K16  = (f16*)(w + (size_t)38 * 1024 * 1024);    // 16 MB
  f16* Vt16 = (f16*)(w + (size_t)54 * 1024 * 1024);    // 16 MB, transposed

  cast_w_kernel<<<dim3(16, 16, 3), 256, 0, stream>>>(Wq, Wk, Wv, Wt);
  cast_x_kernel<<<4096, 256, 0, stream>>>(hidden, X16);
  qkv_gemm_kernel<<<dim3(8, 64, 3), 256, 0, stream>>>(X16, Wt, bq, bk, bv,
                                                      Q16, K16, Vt16);
  flash_kernel<<<4096, 256, 0, stream>>>(Q16, K16, Vt16, mask, out);
}